// Round 1
// baseline (3755.179 us; speedup 1.0000x reference)
//
#include <hip/hip_runtime.h>
#include <math.h>

#define N_NODES 100000
#define N_EDGES 600000
#define DIN     64
#define DH      128
#define NG      512
#define EPS_BN  1e-5f

// ---------------- degree / normalization ----------------
__global__ __launch_bounds__(256) void deg_kernel(const int* __restrict__ dst,
                                                  float* __restrict__ deg, int E) {
    int e = blockIdx.x * blockDim.x + threadIdx.x;
    if (e < E) atomicAdd(&deg[dst[e]], 1.0f);
}

__global__ __launch_bounds__(256) void dis_kernel(float* __restrict__ deg, int n) {
    int i = blockIdx.x * blockDim.x + threadIdx.x;
    if (i < n) deg[i] = rsqrtf(deg[i] + 1.0f);  // +1 = self loop; deg >= 1 always
}

// ---------------- GEMM: C[M,DH] = A[M,K] @ W[K,DH] ----------------
// 256 threads/block, 32 rows/block. Thread = (rg=tid>>5 picks 4 rows, ct=tid&31 picks 4 cols).
template <int K>
__global__ __launch_bounds__(256) void gemm_k(const float* __restrict__ A,
                                              const float* __restrict__ W,
                                              float* __restrict__ C) {
    const int ct = threadIdx.x & 31;
    const int rg = threadIdx.x >> 5;
    const long row0 = (long)blockIdx.x * 32 + rg * 4;

    float acc[4][4];
#pragma unroll
    for (int j = 0; j < 4; ++j)
#pragma unroll
        for (int q = 0; q < 4; ++q) acc[j][q] = 0.0f;

    const float* a0 = A + row0 * K;
    const float* a1 = a0 + K;
    const float* a2 = a1 + K;
    const float* a3 = a2 + K;
    const float* wp = W + ct * 4;

#pragma unroll 2
    for (int k = 0; k < K; k += 4) {
        float4 va[4];
        va[0] = *(const float4*)(a0 + k);
        va[1] = *(const float4*)(a1 + k);
        va[2] = *(const float4*)(a2 + k);
        va[3] = *(const float4*)(a3 + k);
#pragma unroll
        for (int kk = 0; kk < 4; ++kk) {
            const float4 w = *(const float4*)(wp + (long)(k + kk) * DH);
            const float ws[4] = {w.x, w.y, w.z, w.w};
#pragma unroll
            for (int j = 0; j < 4; ++j) {
                const float s = ((const float*)&va[j])[kk];
#pragma unroll
                for (int q = 0; q < 4; ++q) acc[j][q] = fmaf(s, ws[q], acc[j][q]);
            }
        }
    }

#pragma unroll
    for (int j = 0; j < 4; ++j) {
        float4 o;
        o.x = acc[j][0]; o.y = acc[j][1]; o.z = acc[j][2]; o.w = acc[j][3];
        *(float4*)(C + (row0 + j) * DH + ct * 4) = o;
    }
}

// ---------------- edge aggregation: agg[dst] += H[src] * dis[src]*dis[dst] ----------------
__global__ __launch_bounds__(256) void aggregate_kernel(const float* __restrict__ H,
                                                        const int* __restrict__ src,
                                                        const int* __restrict__ dst,
                                                        const float* __restrict__ dis,
                                                        float* __restrict__ agg, int E) {
    long t = (long)blockIdx.x * blockDim.x + threadIdx.x;
    int lane = (int)(t & 31);
    long e = t >> 5;
    if (e >= E) return;
    const int s = src[e];
    const int d = dst[e];
    const float nrm = dis[s] * dis[d];
    const float4 v = *(const float4*)(H + (long)s * DH + lane * 4);
    float* o = agg + (long)d * DH + lane * 4;
    atomicAdd(o + 0, v.x * nrm);
    atomicAdd(o + 1, v.y * nrm);
    atomicAdd(o + 2, v.z * nrm);
    atomicAdd(o + 3, v.w * nrm);
}

// ---------------- BN + bias + self-loop + ReLU (+ residual) ----------------
template <bool RES>
__global__ __launch_bounds__(256) void epilogue_kernel(const float* __restrict__ agg,
                                                       const float* __restrict__ H,
                                                       const float* __restrict__ dis,
                                                       const float* __restrict__ bconv,
                                                       const float* __restrict__ bng,
                                                       const float* __restrict__ bnb,
                                                       const float* __restrict__ bnm,
                                                       const float* __restrict__ bnv,
                                                       float* __restrict__ out, int n) {
    long t = (long)blockIdx.x * blockDim.x + threadIdx.x;
    int lane = (int)(t & 31);
    long i = t >> 5;
    if (i >= n) return;
    const int c = lane * 4;
    float d2 = dis[i];
    d2 *= d2;

    const float4 a  = *(const float4*)(agg   + i * DH + c);
    const float4 h  = *(const float4*)(H     + i * DH + c);
    const float4 bc = *(const float4*)(bconv + c);
    const float4 g  = *(const float4*)(bng   + c);
    const float4 bb = *(const float4*)(bnb   + c);
    const float4 m  = *(const float4*)(bnm   + c);
    const float4 vv = *(const float4*)(bnv   + c);

    float r[4];
    const float av[4] = {a.x, a.y, a.z, a.w};
    const float hv[4] = {h.x, h.y, h.z, h.w};
    const float bcv[4] = {bc.x, bc.y, bc.z, bc.w};
    const float gv[4] = {g.x, g.y, g.z, g.w};
    const float bbv[4] = {bb.x, bb.y, bb.z, bb.w};
    const float mv[4] = {m.x, m.y, m.z, m.w};
    const float vvv[4] = {vv.x, vv.y, vv.z, vv.w};
#pragma unroll
    for (int q = 0; q < 4; ++q) {
        float x = av[q] + hv[q] * d2 + bcv[q];          // conv out (agg + selfloop + bias)
        float sc = gv[q] * rsqrtf(vvv[q] + EPS_BN);
        float y = (x - mv[q]) * sc + bbv[q];
        r[q] = fmaxf(y, 0.0f);
    }
    if (RES) {
        const float4 res = *(const float4*)(out + i * DH + c);
        r[0] += res.x; r[1] += res.y; r[2] += res.z; r[3] += res.w;
    }
    float4 o;
    o.x = r[0]; o.y = r[1]; o.z = r[2]; o.w = r[3];
    *(float4*)(out + i * DH + c) = o;
}

// ---------------- global mean pool (sum + count) ----------------
__global__ __launch_bounds__(256) void pool_kernel(const float* __restrict__ h,
                                                   const int* __restrict__ batch,
                                                   float* __restrict__ pooled,
                                                   float* __restrict__ cnt, int n) {
    long t = (long)blockIdx.x * blockDim.x + threadIdx.x;
    int lane = (int)(t & 31);
    long i = t >> 5;
    if (i >= n) return;
    const int g = batch[i];
    const float4 v = *(const float4*)(h + i * DH + lane * 4);
    float* o = pooled + (long)g * DH + lane * 4;
    atomicAdd(o + 0, v.x);
    atomicAdd(o + 1, v.y);
    atomicAdd(o + 2, v.z);
    atomicAdd(o + 3, v.w);
    if (lane == 0) atomicAdd(&cnt[g], 1.0f);
}

// ---------------- MLP head: relu(p @ fc1 + b1) @ fc2 + b2 -> sigmoid ----------------
__global__ __launch_bounds__(64) void head_kernel(const float* __restrict__ pooled,
                                                  const float* __restrict__ cnt,
                                                  const float* __restrict__ fc1w,
                                                  const float* __restrict__ fc1b,
                                                  const float* __restrict__ fc2w,
                                                  const float* __restrict__ fc2b,
                                                  float* __restrict__ out) {
    const int g = blockIdx.x;
    const int j = threadIdx.x;  // 64 threads = 1 wave
    __shared__ float p[DH];
    const float c = fmaxf(cnt[g], 1.0f);
    p[j]      = pooled[(long)g * DH + j] / c;
    p[j + 64] = pooled[(long)g * DH + 64 + j] / c;
    __syncthreads();

    float acc = 0.0f;
#pragma unroll 4
    for (int k = 0; k < DH; ++k) acc = fmaf(p[k], fc1w[(long)k * 64 + j], acc);
    const float h1 = fmaxf(acc + fc1b[j], 0.0f);
    float v = h1 * fc2w[j];
#pragma unroll
    for (int off = 32; off > 0; off >>= 1) v += __shfl_down(v, off);
    if (j == 0) out[g] = 1.0f / (1.0f + expf(-(v + fc2b[0])));
}

// ---------------- launch ----------------
extern "C" void kernel_launch(void* const* d_in, const int* in_sizes, int n_in,
                              void* d_out, int out_size, void* d_ws, size_t ws_size,
                              hipStream_t stream) {
    const float* x     = (const float*)d_in[0];
    const int*   ei    = (const int*)d_in[1];
    const int*   batch = (const int*)d_in[2];
    const float* W1 = (const float*)d_in[3];
    const float* b1 = (const float*)d_in[4];
    const float* g1 = (const float*)d_in[5];
    const float* t1 = (const float*)d_in[6];
    const float* m1 = (const float*)d_in[7];
    const float* v1 = (const float*)d_in[8];
    const float* W2 = (const float*)d_in[9];
    const float* b2 = (const float*)d_in[10];
    const float* g2 = (const float*)d_in[11];
    const float* t2 = (const float*)d_in[12];
    const float* m2 = (const float*)d_in[13];
    const float* v2 = (const float*)d_in[14];
    const float* W3 = (const float*)d_in[15];
    const float* b3 = (const float*)d_in[16];
    const float* g3 = (const float*)d_in[17];
    const float* t3 = (const float*)d_in[18];
    const float* m3 = (const float*)d_in[19];
    const float* v3 = (const float*)d_in[20];
    const float* fc1w = (const float*)d_in[21];
    const float* fc1b = (const float*)d_in[22];
    const float* fc2w = (const float*)d_in[23];
    const float* fc2b = (const float*)d_in[24];

    const int* src = ei;            // edge_index[0]
    const int* dst = ei + N_EDGES;  // edge_index[1]

    char* ws = (char*)d_ws;
    const size_t NDHB = (size_t)N_NODES * DH * sizeof(float);  // 51,200,000
    float* dis    = (float*)(ws);
    float* bufB   = (float*)(ws + 400384);                  // gemm out
    float* bufC   = (float*)(ws + 400384 + NDHB);           // agg
    float* bufA   = (float*)(ws + 400384 + 2 * NDHB);       // activations
    float* pooled = (float*)(ws + 400384 + 3 * NDHB);
    float* cnt    = (float*)(ws + 400384 + 3 * NDHB + (size_t)NG * DH * sizeof(float));

    const int TPB = 256;
    const int gEdge   = (N_EDGES + TPB - 1) / TPB;
    const int gNode   = (N_NODES + TPB - 1) / TPB;
    const int gGemm   = N_NODES / 32;                 // 3125
    const int gAgg    = (int)(((long)N_EDGES * 32 + TPB - 1) / TPB);   // 75000
    const int gRow32  = (int)(((long)N_NODES * 32 + TPB - 1) / TPB);   // 12500

    // normalization coefficients
    hipMemsetAsync(dis, 0, (size_t)N_NODES * sizeof(float), stream);
    deg_kernel<<<gEdge, TPB, 0, stream>>>(dst, dis, N_EDGES);
    dis_kernel<<<gNode, TPB, 0, stream>>>(dis, N_NODES);

    // ---- layer 1 ----
    gemm_k<DIN><<<gGemm, TPB, 0, stream>>>(x, W1, bufB);
    hipMemsetAsync(bufC, 0, NDHB, stream);
    aggregate_kernel<<<gAgg, TPB, 0, stream>>>(bufB, src, dst, dis, bufC, N_EDGES);
    epilogue_kernel<false><<<gRow32, TPB, 0, stream>>>(bufC, bufB, dis, b1, g1, t1, m1, v1,
                                                       bufA, N_NODES);
    // ---- layer 2 (residual) ----
    gemm_k<DH><<<gGemm, TPB, 0, stream>>>(bufA, W2, bufB);
    hipMemsetAsync(bufC, 0, NDHB, stream);
    aggregate_kernel<<<gAgg, TPB, 0, stream>>>(bufB, src, dst, dis, bufC, N_EDGES);
    epilogue_kernel<true><<<gRow32, TPB, 0, stream>>>(bufC, bufB, dis, b2, g2, t2, m2, v2,
                                                      bufA, N_NODES);
    // ---- layer 3 ----
    gemm_k<DH><<<gGemm, TPB, 0, stream>>>(bufA, W3, bufB);
    hipMemsetAsync(bufC, 0, NDHB, stream);
    aggregate_kernel<<<gAgg, TPB, 0, stream>>>(bufB, src, dst, dis, bufC, N_EDGES);
    epilogue_kernel<false><<<gRow32, TPB, 0, stream>>>(bufC, bufB, dis, b3, g3, t3, m3, v3,
                                                       bufA, N_NODES);

    // ---- pool + head ----
    hipMemsetAsync(pooled, 0, (size_t)NG * DH * sizeof(float), stream);
    hipMemsetAsync(cnt, 0, (size_t)NG * sizeof(float), stream);
    pool_kernel<<<gRow32, TPB, 0, stream>>>(bufA, batch, pooled, cnt, N_NODES);
    head_kernel<<<NG, 64, 0, stream>>>(pooled, cnt, fc1w, fc1b, fc2w, fc2b, (float*)d_out);
}

// Round 2
// 750.032 us; speedup vs baseline: 5.0067x; 5.0067x over previous
//
#include <hip/hip_runtime.h>
#include <math.h>

#define N_NODES 100000
#define N_EDGES 600000
#define DIN     64
#define DH      128
#define NG      512
#define EPS_BN  1e-5f

// ---------------- degree histogram (float counts are exact) ----------------
__global__ __launch_bounds__(256) void deg_kernel(const int* __restrict__ dst,
                                                  float* __restrict__ deg, int E) {
    int e = blockIdx.x * blockDim.x + threadIdx.x;
    if (e < E) atomicAdd(&deg[dst[e]], 1.0f);
}

__global__ __launch_bounds__(256) void dis_kernel(const float* __restrict__ deg,
                                                  float* __restrict__ dis,
                                                  int* __restrict__ deg_i, int n) {
    int i = blockIdx.x * blockDim.x + threadIdx.x;
    if (i < n) {
        float d = deg[i];
        dis[i] = rsqrtf(d + 1.0f);   // +1 self loop, so always >= 1
        deg_i[i] = (int)d;
    }
}

// ---------------- single-block exclusive scan over degrees -> row_ptr ----------------
__global__ __launch_bounds__(1024) void scan_kernel(const int* __restrict__ deg_i,
                                                    int* __restrict__ row_ptr, int n) {
    __shared__ int part[1024];
    const int t = threadIdx.x;
    const int chunk = (n + 1023) / 1024;
    const int beg = t * chunk;
    const int end = min(beg + chunk, n);
    int s = 0;
    for (int i = beg; i < end; ++i) s += deg_i[i];
    part[t] = s;
    __syncthreads();
    // Hillis-Steele inclusive scan
    for (int off = 1; off < 1024; off <<= 1) {
        int u = (t >= off) ? part[t - off] : 0;
        __syncthreads();
        part[t] += u;
        __syncthreads();
    }
    int run = part[t] - s;  // exclusive prefix for this thread's chunk
    for (int i = beg; i < end; ++i) {
        row_ptr[i] = run;
        run += deg_i[i];
    }
    if (t == 1023) row_ptr[n] = part[1023];
}

// ---------------- scatter edges into CSR (dst-sorted) ----------------
__global__ __launch_bounds__(256) void build_csr_kernel(const int* __restrict__ src,
                                                        const int* __restrict__ dst,
                                                        const float* __restrict__ dis,
                                                        const int* __restrict__ row_ptr,
                                                        int* __restrict__ cursor,
                                                        int* __restrict__ col,
                                                        float* __restrict__ val, int E) {
    int e = blockIdx.x * blockDim.x + threadIdx.x;
    if (e >= E) return;
    const int s = src[e];
    const int d = dst[e];
    const int p = atomicAdd(&cursor[d], 1);
    const int idx = row_ptr[d] + p;
    col[idx] = s;
    val[idx] = dis[s] * dis[d];
}

// ---------------- GEMM: C[M,DH] = A[M,K] @ W[K,DH] ----------------
template <int K>
__global__ __launch_bounds__(256) void gemm_k(const float* __restrict__ A,
                                              const float* __restrict__ W,
                                              float* __restrict__ C) {
    const int ct = threadIdx.x & 31;
    const int rg = threadIdx.x >> 5;
    const long row0 = (long)blockIdx.x * 32 + rg * 4;

    float acc[4][4];
#pragma unroll
    for (int j = 0; j < 4; ++j)
#pragma unroll
        for (int q = 0; q < 4; ++q) acc[j][q] = 0.0f;

    const float* a0 = A + row0 * K;
    const float* a1 = a0 + K;
    const float* a2 = a1 + K;
    const float* a3 = a2 + K;
    const float* wp = W + ct * 4;

#pragma unroll 2
    for (int k = 0; k < K; k += 4) {
        float4 va[4];
        va[0] = *(const float4*)(a0 + k);
        va[1] = *(const float4*)(a1 + k);
        va[2] = *(const float4*)(a2 + k);
        va[3] = *(const float4*)(a3 + k);
#pragma unroll
        for (int kk = 0; kk < 4; ++kk) {
            const float4 w = *(const float4*)(wp + (long)(k + kk) * DH);
            const float ws[4] = {w.x, w.y, w.z, w.w};
#pragma unroll
            for (int j = 0; j < 4; ++j) {
                const float s = ((const float*)&va[j])[kk];
#pragma unroll
                for (int q = 0; q < 4; ++q) acc[j][q] = fmaf(s, ws[q], acc[j][q]);
            }
        }
    }

#pragma unroll
    for (int j = 0; j < 4; ++j) {
        float4 o;
        o.x = acc[j][0]; o.y = acc[j][1]; o.z = acc[j][2]; o.w = acc[j][3];
        *(float4*)(C + (row0 + j) * DH + ct * 4) = o;
    }
}

// ---------- fused: agg = CSR-gather-sum + selfloop; out = relu(bn(agg+b)) [+res] ----------
template <bool RES>
__global__ __launch_bounds__(256) void agg_epi_kernel(const float* __restrict__ H,
                                                      const int* __restrict__ row_ptr,
                                                      const int* __restrict__ col,
                                                      const float* __restrict__ val,
                                                      const float* __restrict__ dis,
                                                      const float* __restrict__ bconv,
                                                      const float* __restrict__ bng,
                                                      const float* __restrict__ bnb,
                                                      const float* __restrict__ bnm,
                                                      const float* __restrict__ bnv,
                                                      float* __restrict__ out, int n) {
    const long t = (long)blockIdx.x * blockDim.x + threadIdx.x;
    const int lane = (int)(t & 31);
    const long i = t >> 5;
    if (i >= n) return;
    const int c = lane * 4;

    float d2 = dis[i];
    d2 *= d2;
    const float4 hv = *(const float4*)(H + i * DH + c);
    float acc[4] = {hv.x * d2, hv.y * d2, hv.z * d2, hv.w * d2};  // self-loop

    const int beg = row_ptr[i];
    const int end = row_ptr[i + 1];
    for (int e = beg; e < end; ++e) {
        const int s = col[e];
        const float nm = val[e];
        const float4 v = *(const float4*)(H + (long)s * DH + c);
        acc[0] = fmaf(v.x, nm, acc[0]);
        acc[1] = fmaf(v.y, nm, acc[1]);
        acc[2] = fmaf(v.z, nm, acc[2]);
        acc[3] = fmaf(v.w, nm, acc[3]);
    }

    const float4 bc = *(const float4*)(bconv + c);
    const float4 g  = *(const float4*)(bng   + c);
    const float4 bb = *(const float4*)(bnb   + c);
    const float4 m  = *(const float4*)(bnm   + c);
    const float4 vv = *(const float4*)(bnv   + c);
    const float bcv[4] = {bc.x, bc.y, bc.z, bc.w};
    const float gv[4]  = {g.x, g.y, g.z, g.w};
    const float bbv[4] = {bb.x, bb.y, bb.z, bb.w};
    const float mv[4]  = {m.x, m.y, m.z, m.w};
    const float vvv[4] = {vv.x, vv.y, vv.z, vv.w};

    float r[4];
#pragma unroll
    for (int q = 0; q < 4; ++q) {
        const float x = acc[q] + bcv[q];
        const float sc = gv[q] * rsqrtf(vvv[q] + EPS_BN);
        const float y = (x - mv[q]) * sc + bbv[q];
        r[q] = fmaxf(y, 0.0f);
    }
    if (RES) {
        const float4 res = *(const float4*)(out + i * DH + c);
        r[0] += res.x; r[1] += res.y; r[2] += res.z; r[3] += res.w;
    }
    float4 o;
    o.x = r[0]; o.y = r[1]; o.z = r[2]; o.w = r[3];
    *(float4*)(out + i * DH + c) = o;
}

// ---------------- per-graph boundaries (batch is sorted) ----------------
__global__ __launch_bounds__(256) void graph_bounds_kernel(const int* __restrict__ batch,
                                                           int* __restrict__ gp) {
    int g = blockIdx.x * blockDim.x + threadIdx.x;
    if (g > NG) return;
    int lo = 0, hi = N_NODES;
    while (lo < hi) {
        int mid = (lo + hi) >> 1;
        if (batch[mid] < g) lo = mid + 1; else hi = mid;
    }
    gp[g] = lo;
}

// ---------------- segmented mean pool ----------------
__global__ __launch_bounds__(128) void pool_kernel(const float* __restrict__ h,
                                                   const int* __restrict__ gp,
                                                   float* __restrict__ pooled) {
    const int g = blockIdx.x;
    const int j = threadIdx.x;  // channel
    const int beg = gp[g];
    const int end = gp[g + 1];
    float s = 0.0f;
    for (int i = beg; i < end; ++i) s += h[(long)i * DH + j];
    const float c = fmaxf((float)(end - beg), 1.0f);
    pooled[(long)g * DH + j] = s / c;
}

// ---------------- MLP head ----------------
__global__ __launch_bounds__(64) void head_kernel(const float* __restrict__ pooled,
                                                  const float* __restrict__ fc1w,
                                                  const float* __restrict__ fc1b,
                                                  const float* __restrict__ fc2w,
                                                  const float* __restrict__ fc2b,
                                                  float* __restrict__ out) {
    const int g = blockIdx.x;
    const int j = threadIdx.x;  // 64 threads = 1 wave
    __shared__ float p[DH];
    p[j]      = pooled[(long)g * DH + j];
    p[j + 64] = pooled[(long)g * DH + 64 + j];
    __syncthreads();

    float acc = 0.0f;
#pragma unroll 4
    for (int k = 0; k < DH; ++k) acc = fmaf(p[k], fc1w[(long)k * 64 + j], acc);
    const float h1 = fmaxf(acc + fc1b[j], 0.0f);
    float v = h1 * fc2w[j];
#pragma unroll
    for (int off = 32; off > 0; off >>= 1) v += __shfl_down(v, off);
    if (j == 0) out[g] = 1.0f / (1.0f + expf(-(v + fc2b[0])));
}

// ---------------- launch ----------------
extern "C" void kernel_launch(void* const* d_in, const int* in_sizes, int n_in,
                              void* d_out, int out_size, void* d_ws, size_t ws_size,
                              hipStream_t stream) {
    const float* x     = (const float*)d_in[0];
    const int*   ei    = (const int*)d_in[1];
    const int*   batch = (const int*)d_in[2];
    const float* W1 = (const float*)d_in[3];
    const float* b1 = (const float*)d_in[4];
    const float* g1 = (const float*)d_in[5];
    const float* t1 = (const float*)d_in[6];
    const float* m1 = (const float*)d_in[7];
    const float* v1 = (const float*)d_in[8];
    const float* W2 = (const float*)d_in[9];
    const float* b2 = (const float*)d_in[10];
    const float* g2 = (const float*)d_in[11];
    const float* t2 = (const float*)d_in[12];
    const float* m2 = (const float*)d_in[13];
    const float* v2 = (const float*)d_in[14];
    const float* W3 = (const float*)d_in[15];
    const float* b3 = (const float*)d_in[16];
    const float* g3 = (const float*)d_in[17];
    const float* t3 = (const float*)d_in[18];
    const float* m3 = (const float*)d_in[19];
    const float* v3 = (const float*)d_in[20];
    const float* fc1w = (const float*)d_in[21];
    const float* fc1b = (const float*)d_in[22];
    const float* fc2w = (const float*)d_in[23];
    const float* fc2b = (const float*)d_in[24];

    const int* src = ei;            // edge_index[0]
    const int* dst = ei + N_EDGES;  // edge_index[1]

    // ---- workspace layout (512B aligned blocks) ----
    char* ws = (char*)d_ws;
    size_t off = 0;
    auto alloc = [&](size_t bytes) -> char* {
        char* p = ws + off;
        off = (off + bytes + 511) & ~(size_t)511;
        return p;
    };
    float* deg     = (float*)alloc((size_t)N_NODES * 4);
    float* dis     = (float*)alloc((size_t)N_NODES * 4);
    int*   deg_i   = (int*)  alloc((size_t)N_NODES * 4);
    int*   row_ptr = (int*)  alloc(((size_t)N_NODES + 1) * 4);
    int*   cursor  = (int*)  alloc((size_t)N_NODES * 4);
    int*   col     = (int*)  alloc((size_t)N_EDGES * 4);
    float* val     = (float*)alloc((size_t)N_EDGES * 4);
    int*   gp      = (int*)  alloc((size_t)(NG + 1) * 4);
    float* pooled  = (float*)alloc((size_t)NG * DH * 4);
    float* bufB    = (float*)alloc((size_t)N_NODES * DH * 4);
    float* bufA    = (float*)alloc((size_t)N_NODES * DH * 4);

    const int TPB = 256;
    const int gEdge  = (N_EDGES + TPB - 1) / TPB;
    const int gNode  = (N_NODES + TPB - 1) / TPB;
    const int gGemm  = N_NODES / 32;
    const int gRow32 = (int)(((long)N_NODES * 32 + TPB - 1) / TPB);

    // ---- graph structure prep (per call; deterministic) ----
    hipMemsetAsync(deg, 0, (size_t)N_NODES * 4, stream);
    hipMemsetAsync(cursor, 0, (size_t)N_NODES * 4, stream);
    deg_kernel<<<gEdge, TPB, 0, stream>>>(dst, deg, N_EDGES);
    dis_kernel<<<gNode, TPB, 0, stream>>>(deg, dis, deg_i, N_NODES);
    scan_kernel<<<1, 1024, 0, stream>>>(deg_i, row_ptr, N_NODES);
    build_csr_kernel<<<gEdge, TPB, 0, stream>>>(src, dst, dis, row_ptr, cursor, col, val,
                                                N_EDGES);
    graph_bounds_kernel<<<3, 256, 0, stream>>>(batch, gp);

    // ---- layer 1 ----
    gemm_k<DIN><<<gGemm, TPB, 0, stream>>>(x, W1, bufB);
    agg_epi_kernel<false><<<gRow32, TPB, 0, stream>>>(bufB, row_ptr, col, val, dis,
                                                      b1, g1, t1, m1, v1, bufA, N_NODES);
    // ---- layer 2 (residual, in-place on bufA) ----
    gemm_k<DH><<<gGemm, TPB, 0, stream>>>(bufA, W2, bufB);
    agg_epi_kernel<true><<<gRow32, TPB, 0, stream>>>(bufB, row_ptr, col, val, dis,
                                                     b2, g2, t2, m2, v2, bufA, N_NODES);
    // ---- layer 3 ----
    gemm_k<DH><<<gGemm, TPB, 0, stream>>>(bufA, W3, bufB);
    agg_epi_kernel<false><<<gRow32, TPB, 0, stream>>>(bufB, row_ptr, col, val, dis,
                                                      b3, g3, t3, m3, v3, bufA, N_NODES);

    // ---- pool + head ----
    pool_kernel<<<NG, 128, 0, stream>>>(bufA, gp, pooled);
    head_kernel<<<NG, 64, 0, stream>>>(pooled, fc1w, fc1b, fc2w, fc2b, (float*)d_out);
}

// Round 3
// 600.433 us; speedup vs baseline: 6.2541x; 1.2492x over previous
//
#include <hip/hip_runtime.h>
#include <math.h>

#define N_NODES 100000
#define N_EDGES 600000
#define DIN     64
#define DH      128
#define NG      512
#define EPS_BN  1e-5f
#define SCAN_TPB 256
#define N_SCAN_BLK ((N_NODES + SCAN_TPB - 1) / SCAN_TPB)   // 391

// ---------------- degree histogram ----------------
__global__ __launch_bounds__(256) void deg_kernel(const int* __restrict__ dst,
                                                  float* __restrict__ deg, int E) {
    int e = blockIdx.x * blockDim.x + threadIdx.x;
    if (e < E) atomicAdd(&deg[dst[e]], 1.0f);
}

__global__ __launch_bounds__(256) void dis_kernel(const float* __restrict__ deg,
                                                  float* __restrict__ dis,
                                                  int* __restrict__ deg_i, int n) {
    int i = blockIdx.x * blockDim.x + threadIdx.x;
    if (i < n) {
        float d = deg[i];
        dis[i] = rsqrtf(d + 1.0f);   // +1 self loop, so always >= 1
        deg_i[i] = (int)d;
    }
}

// ---------------- multi-block scan: phase 1 (local scan + block sums) ----------------
__global__ __launch_bounds__(SCAN_TPB) void scan1_kernel(const int* __restrict__ deg_i,
                                                         int* __restrict__ row_ptr,
                                                         int* __restrict__ blk, int n) {
    __shared__ int sm[SCAN_TPB];
    const int t = threadIdx.x;
    const int i = blockIdx.x * SCAN_TPB + t;
    const int v = (i < n) ? deg_i[i] : 0;
    sm[t] = v;
    __syncthreads();
#pragma unroll
    for (int off = 1; off < SCAN_TPB; off <<= 1) {
        int u = (t >= off) ? sm[t - off] : 0;
        __syncthreads();
        sm[t] += u;
        __syncthreads();
    }
    if (i < n) row_ptr[i] = sm[t] - v;           // exclusive local prefix
    if (t == SCAN_TPB - 1) blk[blockIdx.x] = sm[t];
}

// ---------------- phase 2: scan block sums (single small block) ----------------
__global__ __launch_bounds__(512) void scan2_kernel(int* __restrict__ blk,
                                                    int* __restrict__ row_ptr,
                                                    int nblk, int n) {
    __shared__ int sm[512];
    const int t = threadIdx.x;
    const int v = (t < nblk) ? blk[t] : 0;
    sm[t] = v;
    __syncthreads();
#pragma unroll
    for (int off = 1; off < 512; off <<= 1) {
        int u = (t >= off) ? sm[t - off] : 0;
        __syncthreads();
        sm[t] += u;
        __syncthreads();
    }
    if (t < nblk) blk[t] = sm[t] - v;            // exclusive prefix of block sums
    if (t == nblk - 1) row_ptr[n] = sm[t];       // total edge count
}

// ---------------- phase 3: add block offsets ----------------
__global__ __launch_bounds__(SCAN_TPB) void scan3_kernel(int* __restrict__ row_ptr,
                                                         const int* __restrict__ blk, int n) {
    const int i = blockIdx.x * SCAN_TPB + threadIdx.x;
    if (i < n) row_ptr[i] += blk[blockIdx.x];
}

// ---------------- scatter edges into CSR (dst-sorted) ----------------
__global__ __launch_bounds__(256) void build_csr_kernel(const int* __restrict__ src,
                                                        const int* __restrict__ dst,
                                                        const float* __restrict__ dis,
                                                        const int* __restrict__ row_ptr,
                                                        int* __restrict__ cursor,
                                                        int* __restrict__ col,
                                                        float* __restrict__ val, int E) {
    int e = blockIdx.x * blockDim.x + threadIdx.x;
    if (e >= E) return;
    const int s = src[e];
    const int d = dst[e];
    const int p = atomicAdd(&cursor[d], 1);
    const int idx = row_ptr[d] + p;
    col[idx] = s;
    val[idx] = dis[s] * dis[d];
}

// ---------------- GEMM: C[M,DH] = A[M,K] @ W[K,DH] ----------------
template <int K>
__global__ __launch_bounds__(256) void gemm_k(const float* __restrict__ A,
                                              const float* __restrict__ W,
                                              float* __restrict__ C) {
    const int ct = threadIdx.x & 31;
    const int rg = threadIdx.x >> 5;
    const long row0 = (long)blockIdx.x * 32 + rg * 4;

    float acc[4][4];
#pragma unroll
    for (int j = 0; j < 4; ++j)
#pragma unroll
        for (int q = 0; q < 4; ++q) acc[j][q] = 0.0f;

    const float* a0 = A + row0 * K;
    const float* a1 = a0 + K;
    const float* a2 = a1 + K;
    const float* a3 = a2 + K;
    const float* wp = W + ct * 4;

#pragma unroll 2
    for (int k = 0; k < K; k += 4) {
        float4 va[4];
        va[0] = *(const float4*)(a0 + k);
        va[1] = *(const float4*)(a1 + k);
        va[2] = *(const float4*)(a2 + k);
        va[3] = *(const float4*)(a3 + k);
#pragma unroll
        for (int kk = 0; kk < 4; ++kk) {
            const float4 w = *(const float4*)(wp + (long)(k + kk) * DH);
            const float ws[4] = {w.x, w.y, w.z, w.w};
#pragma unroll
            for (int j = 0; j < 4; ++j) {
                const float s = ((const float*)&va[j])[kk];
#pragma unroll
                for (int q = 0; q < 4; ++q) acc[j][q] = fmaf(s, ws[q], acc[j][q]);
            }
        }
    }

#pragma unroll
    for (int j = 0; j < 4; ++j) {
        float4 o;
        o.x = acc[j][0]; o.y = acc[j][1]; o.z = acc[j][2]; o.w = acc[j][3];
        *(float4*)(C + (row0 + j) * DH + ct * 4) = o;
    }
}

// ---------- fused: agg = CSR-gather-sum + selfloop; out = relu(bn(agg+b)) [+res] ----------
template <bool RES>
__global__ __launch_bounds__(256) void agg_epi_kernel(const float* __restrict__ H,
                                                      const int* __restrict__ row_ptr,
                                                      const int* __restrict__ col,
                                                      const float* __restrict__ val,
                                                      const float* __restrict__ dis,
                                                      const float* __restrict__ bconv,
                                                      const float* __restrict__ bng,
                                                      const float* __restrict__ bnb,
                                                      const float* __restrict__ bnm,
                                                      const float* __restrict__ bnv,
                                                      float* __restrict__ out, int n) {
    const long t = (long)blockIdx.x * blockDim.x + threadIdx.x;
    const int lane = (int)(t & 31);
    const long i = t >> 5;
    if (i >= n) return;
    const int c = lane * 4;

    float d2 = dis[i];
    d2 *= d2;
    const float4 hv = *(const float4*)(H + i * DH + c);
    float acc[4] = {hv.x * d2, hv.y * d2, hv.z * d2, hv.w * d2};  // self-loop

    const int beg = row_ptr[i];
    const int end = row_ptr[i + 1];
    for (int e = beg; e < end; ++e) {
        const int s = col[e];
        const float nm = val[e];
        const float4 v = *(const float4*)(H + (long)s * DH + c);
        acc[0] = fmaf(v.x, nm, acc[0]);
        acc[1] = fmaf(v.y, nm, acc[1]);
        acc[2] = fmaf(v.z, nm, acc[2]);
        acc[3] = fmaf(v.w, nm, acc[3]);
    }

    const float4 bc = *(const float4*)(bconv + c);
    const float4 g  = *(const float4*)(bng   + c);
    const float4 bb = *(const float4*)(bnb   + c);
    const float4 m  = *(const float4*)(bnm   + c);
    const float4 vv = *(const float4*)(bnv   + c);
    const float bcv[4] = {bc.x, bc.y, bc.z, bc.w};
    const float gv[4]  = {g.x, g.y, g.z, g.w};
    const float bbv[4] = {bb.x, bb.y, bb.z, bb.w};
    const float mv[4]  = {m.x, m.y, m.z, m.w};
    const float vvv[4] = {vv.x, vv.y, vv.z, vv.w};

    float r[4];
#pragma unroll
    for (int q = 0; q < 4; ++q) {
        const float x = acc[q] + bcv[q];
        const float sc = gv[q] * rsqrtf(vvv[q] + EPS_BN);
        const float y = (x - mv[q]) * sc + bbv[q];
        r[q] = fmaxf(y, 0.0f);
    }
    if (RES) {
        const float4 res = *(const float4*)(out + i * DH + c);
        r[0] += res.x; r[1] += res.y; r[2] += res.z; r[3] += res.w;
    }
    float4 o;
    o.x = r[0]; o.y = r[1]; o.z = r[2]; o.w = r[3];
    *(float4*)(out + i * DH + c) = o;
}

// ---------------- per-graph boundaries (batch is sorted) ----------------
__global__ __launch_bounds__(256) void graph_bounds_kernel(const int* __restrict__ batch,
                                                           int* __restrict__ gp) {
    int g = blockIdx.x * blockDim.x + threadIdx.x;
    if (g > NG) return;
    int lo = 0, hi = N_NODES;
    while (lo < hi) {
        int mid = (lo + hi) >> 1;
        if (batch[mid] < g) lo = mid + 1; else hi = mid;
    }
    gp[g] = lo;
}

// ---------------- segmented mean pool ----------------
__global__ __launch_bounds__(128) void pool_kernel(const float* __restrict__ h,
                                                   const int* __restrict__ gp,
                                                   float* __restrict__ pooled) {
    const int g = blockIdx.x;
    const int j = threadIdx.x;  // channel
    const int beg = gp[g];
    const int end = gp[g + 1];
    float s = 0.0f;
    for (int i = beg; i < end; ++i) s += h[(long)i * DH + j];
    const float c = fmaxf((float)(end - beg), 1.0f);
    pooled[(long)g * DH + j] = s / c;
}

// ---------------- MLP head ----------------
__global__ __launch_bounds__(64) void head_kernel(const float* __restrict__ pooled,
                                                  const float* __restrict__ fc1w,
                                                  const float* __restrict__ fc1b,
                                                  const float* __restrict__ fc2w,
                                                  const float* __restrict__ fc2b,
                                                  float* __restrict__ out) {
    const int g = blockIdx.x;
    const int j = threadIdx.x;  // 64 threads = 1 wave
    __shared__ float p[DH];
    p[j]      = pooled[(long)g * DH + j];
    p[j + 64] = pooled[(long)g * DH + 64 + j];
    __syncthreads();

    float acc = 0.0f;
#pragma unroll 4
    for (int k = 0; k < DH; ++k) acc = fmaf(p[k], fc1w[(long)k * 64 + j], acc);
    const float h1 = fmaxf(acc + fc1b[j], 0.0f);
    float v = h1 * fc2w[j];
#pragma unroll
    for (int off = 32; off > 0; off >>= 1) v += __shfl_down(v, off);
    if (j == 0) out[g] = 1.0f / (1.0f + expf(-(v + fc2b[0])));
}

// ---------------- launch ----------------
extern "C" void kernel_launch(void* const* d_in, const int* in_sizes, int n_in,
                              void* d_out, int out_size, void* d_ws, size_t ws_size,
                              hipStream_t stream) {
    const float* x     = (const float*)d_in[0];
    const int*   ei    = (const int*)d_in[1];
    const int*   batch = (const int*)d_in[2];
    const float* W1 = (const float*)d_in[3];
    const float* b1 = (const float*)d_in[4];
    const float* g1 = (const float*)d_in[5];
    const float* t1 = (const float*)d_in[6];
    const float* m1 = (const float*)d_in[7];
    const float* v1 = (const float*)d_in[8];
    const float* W2 = (const float*)d_in[9];
    const float* b2 = (const float*)d_in[10];
    const float* g2 = (const float*)d_in[11];
    const float* t2 = (const float*)d_in[12];
    const float* m2 = (const float*)d_in[13];
    const float* v2 = (const float*)d_in[14];
    const float* W3 = (const float*)d_in[15];
    const float* b3 = (const float*)d_in[16];
    const float* g3 = (const float*)d_in[17];
    const float* t3 = (const float*)d_in[18];
    const float* m3 = (const float*)d_in[19];
    const float* v3 = (const float*)d_in[20];
    const float* fc1w = (const float*)d_in[21];
    const float* fc1b = (const float*)d_in[22];
    const float* fc2w = (const float*)d_in[23];
    const float* fc2b = (const float*)d_in[24];

    const int* src = ei;            // edge_index[0]
    const int* dst = ei + N_EDGES;  // edge_index[1]

    // ---- workspace layout (512B aligned blocks) ----
    char* ws = (char*)d_ws;
    size_t off = 0;
    auto alloc = [&](size_t bytes) -> char* {
        char* p = ws + off;
        off = (off + bytes + 511) & ~(size_t)511;
        return p;
    };
    float* deg     = (float*)alloc((size_t)N_NODES * 4);
    float* dis     = (float*)alloc((size_t)N_NODES * 4);
    int*   deg_i   = (int*)  alloc((size_t)N_NODES * 4);
    int*   row_ptr = (int*)  alloc(((size_t)N_NODES + 1) * 4);
    int*   cursor  = (int*)  alloc((size_t)N_NODES * 4);
    int*   blk     = (int*)  alloc((size_t)N_SCAN_BLK * 4);
    int*   col     = (int*)  alloc((size_t)N_EDGES * 4);
    float* val     = (float*)alloc((size_t)N_EDGES * 4);
    int*   gp      = (int*)  alloc((size_t)(NG + 1) * 4);
    float* pooled  = (float*)alloc((size_t)NG * DH * 4);
    float* bufB    = (float*)alloc((size_t)N_NODES * DH * 4);
    float* bufA    = (float*)alloc((size_t)N_NODES * DH * 4);

    const int TPB = 256;
    const int gEdge  = (N_EDGES + TPB - 1) / TPB;
    const int gNode  = (N_NODES + TPB - 1) / TPB;
    const int gGemm  = N_NODES / 32;
    const int gRow32 = (int)(((long)N_NODES * 32 + TPB - 1) / TPB);

    // ---- graph structure prep (per call; deterministic) ----
    hipMemsetAsync(deg, 0, (size_t)N_NODES * 4, stream);
    hipMemsetAsync(cursor, 0, (size_t)N_NODES * 4, stream);
    deg_kernel<<<gEdge, TPB, 0, stream>>>(dst, deg, N_EDGES);
    dis_kernel<<<gNode, TPB, 0, stream>>>(deg, dis, deg_i, N_NODES);
    scan1_kernel<<<N_SCAN_BLK, SCAN_TPB, 0, stream>>>(deg_i, row_ptr, blk, N_NODES);
    scan2_kernel<<<1, 512, 0, stream>>>(blk, row_ptr, N_SCAN_BLK, N_NODES);
    scan3_kernel<<<N_SCAN_BLK, SCAN_TPB, 0, stream>>>(row_ptr, blk, N_NODES);
    build_csr_kernel<<<gEdge, TPB, 0, stream>>>(src, dst, dis, row_ptr, cursor, col, val,
                                                N_EDGES);
    graph_bounds_kernel<<<3, 256, 0, stream>>>(batch, gp);

    // ---- layer 1 ----
    gemm_k<DIN><<<gGemm, TPB, 0, stream>>>(x, W1, bufB);
    agg_epi_kernel<false><<<gRow32, TPB, 0, stream>>>(bufB, row_ptr, col, val, dis,
                                                      b1, g1, t1, m1, v1, bufA, N_NODES);
    // ---- layer 2 (residual, in-place on bufA) ----
    gemm_k<DH><<<gGemm, TPB, 0, stream>>>(bufA, W2, bufB);
    agg_epi_kernel<true><<<gRow32, TPB, 0, stream>>>(bufB, row_ptr, col, val, dis,
                                                     b2, g2, t2, m2, v2, bufA, N_NODES);
    // ---- layer 3 ----
    gemm_k<DH><<<gGemm, TPB, 0, stream>>>(bufA, W3, bufB);
    agg_epi_kernel<false><<<gRow32, TPB, 0, stream>>>(bufB, row_ptr, col, val, dis,
                                                      b3, g3, t3, m3, v3, bufA, N_NODES);

    // ---- pool + head ----
    pool_kernel<<<NG, 128, 0, stream>>>(bufA, gp, pooled);
    head_kernel<<<NG, 64, 0, stream>>>(pooled, fc1w, fc1b, fc2w, fc2b, (float*)d_out);
}

// Round 4
// 377.836 us; speedup vs baseline: 9.9387x; 1.5891x over previous
//
#include <hip/hip_runtime.h>
#include <math.h>

#define N_NODES 100000
#define N_EDGES 600000
#define DIN     64
#define DH      128
#define NG      512
#define EPS_BN  1e-5f
#define SCAN_TPB 256
#define N_SCAN_BLK ((N_NODES + SCAN_TPB - 1) / SCAN_TPB)   // 391

typedef unsigned short u16;
typedef short s16x8 __attribute__((ext_vector_type(8)));
typedef float f32x4 __attribute__((ext_vector_type(4)));

__device__ __forceinline__ u16 f2bf(float x) {
    unsigned u = __builtin_bit_cast(unsigned, x);
    u += 0x7fffu + ((u >> 16) & 1u);   // round-to-nearest-even
    return (u16)(u >> 16);
}
__device__ __forceinline__ float bf2f(u16 h) {
    unsigned u = ((unsigned)h) << 16;
    return __builtin_bit_cast(float, u);
}

// ---------------- degree histogram ----------------
__global__ __launch_bounds__(256) void deg_kernel(const int* __restrict__ dst,
                                                  float* __restrict__ deg, int E) {
    int e = blockIdx.x * blockDim.x + threadIdx.x;
    if (e < E) atomicAdd(&deg[dst[e]], 1.0f);
}

__global__ __launch_bounds__(256) void dis_kernel(const float* __restrict__ deg,
                                                  float* __restrict__ dis,
                                                  int* __restrict__ deg_i, int n) {
    int i = blockIdx.x * blockDim.x + threadIdx.x;
    if (i < n) {
        float d = deg[i];
        dis[i] = rsqrtf(d + 1.0f);   // +1 self loop
        deg_i[i] = (int)d;
    }
}

// ---------------- multi-block scan ----------------
__global__ __launch_bounds__(SCAN_TPB) void scan1_kernel(const int* __restrict__ deg_i,
                                                         int* __restrict__ row_ptr,
                                                         int* __restrict__ blk, int n) {
    __shared__ int sm[SCAN_TPB];
    const int t = threadIdx.x;
    const int i = blockIdx.x * SCAN_TPB + t;
    const int v = (i < n) ? deg_i[i] : 0;
    sm[t] = v;
    __syncthreads();
#pragma unroll
    for (int off = 1; off < SCAN_TPB; off <<= 1) {
        int u = (t >= off) ? sm[t - off] : 0;
        __syncthreads();
        sm[t] += u;
        __syncthreads();
    }
    if (i < n) row_ptr[i] = sm[t] - v;
    if (t == SCAN_TPB - 1) blk[blockIdx.x] = sm[t];
}

__global__ __launch_bounds__(512) void scan2_kernel(int* __restrict__ blk,
                                                    int* __restrict__ row_ptr,
                                                    int nblk, int n) {
    __shared__ int sm[512];
    const int t = threadIdx.x;
    const int v = (t < nblk) ? blk[t] : 0;
    sm[t] = v;
    __syncthreads();
#pragma unroll
    for (int off = 1; off < 512; off <<= 1) {
        int u = (t >= off) ? sm[t - off] : 0;
        __syncthreads();
        sm[t] += u;
        __syncthreads();
    }
    if (t < nblk) blk[t] = sm[t] - v;
    if (t == nblk - 1) row_ptr[n] = sm[t];
}

__global__ __launch_bounds__(SCAN_TPB) void scan3_kernel(int* __restrict__ row_ptr,
                                                         const int* __restrict__ blk, int n) {
    const int i = blockIdx.x * SCAN_TPB + threadIdx.x;
    if (i < n) row_ptr[i] += blk[blockIdx.x];
}

// ---------------- scatter edges into CSR ----------------
__global__ __launch_bounds__(256) void build_csr_kernel(const int* __restrict__ src,
                                                        const int* __restrict__ dst,
                                                        const float* __restrict__ dis,
                                                        const int* __restrict__ row_ptr,
                                                        int* __restrict__ cursor,
                                                        int* __restrict__ col,
                                                        float* __restrict__ val, int E) {
    int e = blockIdx.x * blockDim.x + threadIdx.x;
    if (e >= E) return;
    const int s = src[e];
    const int d = dst[e];
    const int p = atomicAdd(&cursor[d], 1);
    const int idx = row_ptr[d] + p;
    col[idx] = s;
    val[idx] = dis[s] * dis[d];
}

// ---------------- fp32 -> bf16 convert (x) ----------------
__global__ __launch_bounds__(256) void xcvt_kernel(const float* __restrict__ x,
                                                   u16* __restrict__ xb, long n) {
    long i = ((long)blockIdx.x * blockDim.x + threadIdx.x) * 8;
    if (i >= n) return;
    const float4 a = *(const float4*)(x + i);
    const float4 b = *(const float4*)(x + i + 4);
    s16x8 o;
    o[0] = (short)f2bf(a.x); o[1] = (short)f2bf(a.y);
    o[2] = (short)f2bf(a.z); o[3] = (short)f2bf(a.w);
    o[4] = (short)f2bf(b.x); o[5] = (short)f2bf(b.y);
    o[6] = (short)f2bf(b.z); o[7] = (short)f2bf(b.w);
    *(s16x8*)(xb + i) = o;
}

// ---------------- W[K][N] fp32 -> Wt[N][K] bf16 ----------------
__global__ __launch_bounds__(256) void wt_kernel(const float* __restrict__ W,
                                                 u16* __restrict__ Wt, int K, int N) {
    int idx = blockIdx.x * blockDim.x + threadIdx.x;
    if (idx >= K * N) return;
    int k = idx / N, n = idx % N;
    Wt[(long)n * K + k] = f2bf(W[idx]);
}

// ---------------- fold BN into scale/shift (3 layers) ----------------
__global__ __launch_bounds__(256) void bn_prep_kernel(
    const float* b1, const float* g1, const float* bb1, const float* m1, const float* v1,
    const float* b2, const float* g2, const float* bb2, const float* m2, const float* v2,
    const float* b3, const float* g3, const float* bb3, const float* m3, const float* v3,
    float* __restrict__ sc, float* __restrict__ sh) {
    int i = blockIdx.x * blockDim.x + threadIdx.x;
    if (i >= 3 * DH) return;
    int l = i >> 7, c = i & (DH - 1);
    const float* bc = l == 0 ? b1 : (l == 1 ? b2 : b3);
    const float* g  = l == 0 ? g1 : (l == 1 ? g2 : g3);
    const float* bb = l == 0 ? bb1 : (l == 1 ? bb2 : bb3);
    const float* m  = l == 0 ? m1 : (l == 1 ? m2 : m3);
    const float* v  = l == 0 ? v1 : (l == 1 ? v2 : v3);
    float s = g[c] * rsqrtf(v[c] + EPS_BN);
    sc[i] = s;
    sh[i] = (bc[c] - m[c]) * s + bb[c];
}

// ---------------- MFMA GEMM: C[M,128] = A[M,K] @ Wt^T, bf16 in/out, fp32 acc ----------------
template <int K>
__global__ __launch_bounds__(256) void gemm_mfma(const u16* __restrict__ A,   // [M][K] bf16
                                                 const u16* __restrict__ Wt,  // [128][K] bf16
                                                 u16* __restrict__ C,         // [M][128] bf16
                                                 int M) {
    const int wave = threadIdx.x >> 6;
    const int lane = threadIdx.x & 63;
    const int r16 = lane & 15;   // A row-in-tile / B col-in-tile
    const int kc  = lane >> 4;   // k-chunk 0..3 (8 bf16 each)
    const long row0 = (long)blockIdx.x * 64 + wave * 16;

    f32x4 acc[8];
#pragma unroll
    for (int t = 0; t < 8; ++t)
#pragma unroll
        for (int q = 0; q < 4; ++q) acc[t][q] = 0.0f;

    long arow = row0 + r16;
    if (arow >= M) arow = M - 1;
    const u16* ap = A + arow * K + kc * 8;

#pragma unroll
    for (int ks = 0; ks < K; ks += 32) {
        const s16x8 a = *(const s16x8*)(ap + ks);
#pragma unroll
        for (int t = 0; t < 8; ++t) {
            const s16x8 b = *(const s16x8*)(Wt + (long)(t * 16 + r16) * K + ks + kc * 8);
            acc[t] = __builtin_amdgcn_mfma_f32_16x16x32_bf16(a, b, acc[t], 0, 0, 0);
        }
    }

    // D: col = t*16 + (lane&15), row = row0 + (lane>>4)*4 + r
#pragma unroll
    for (int r = 0; r < 4; ++r) {
        const long row = row0 + kc * 4 + r;
        if (row < M) {
            u16* cp = C + row * DH + r16;
#pragma unroll
            for (int t = 0; t < 8; ++t) cp[t * 16] = f2bf(acc[t][r]);
        }
    }
}

// ---------- fused: CSR gather-sum + selfloop + BN(scale/shift) + ReLU [+res], bf16 ----------
template <bool RES>
__global__ __launch_bounds__(256) void agg_epi_kernel(const u16* __restrict__ H,
                                                      const int* __restrict__ row_ptr,
                                                      const int* __restrict__ col,
                                                      const float* __restrict__ val,
                                                      const float* __restrict__ dis,
                                                      const float* __restrict__ scl,
                                                      const float* __restrict__ shf,
                                                      u16* __restrict__ out, int n) {
    const long t = (long)blockIdx.x * blockDim.x + threadIdx.x;
    const int lane = (int)(t & 15);
    const long i = t >> 4;
    if (i >= n) return;
    const int c = lane * 8;

    float d2 = dis[i];
    d2 *= d2;
    float acc[8];
    const s16x8 hv = *(const s16x8*)(H + i * DH + c);
#pragma unroll
    for (int q = 0; q < 8; ++q) acc[q] = bf2f((u16)hv[q]) * d2;   // self-loop

    const int beg = row_ptr[i];
    const int end = row_ptr[i + 1];
    for (int e = beg; e < end; ++e) {
        const int s = col[e];
        const float nm = val[e];
        const s16x8 v = *(const s16x8*)(H + (long)s * DH + c);
#pragma unroll
        for (int q = 0; q < 8; ++q) acc[q] = fmaf(bf2f((u16)v[q]), nm, acc[q]);
    }

    const float4 s0 = *(const float4*)(scl + c);
    const float4 s1 = *(const float4*)(scl + c + 4);
    const float4 f0 = *(const float4*)(shf + c);
    const float4 f1 = *(const float4*)(shf + c + 4);
    const float sv[8] = {s0.x, s0.y, s0.z, s0.w, s1.x, s1.y, s1.z, s1.w};
    const float fv[8] = {f0.x, f0.y, f0.z, f0.w, f1.x, f1.y, f1.z, f1.w};

    float r[8];
#pragma unroll
    for (int q = 0; q < 8; ++q) r[q] = fmaxf(fmaf(acc[q], sv[q], fv[q]), 0.0f);
    if (RES) {
        const s16x8 rv = *(const s16x8*)(out + i * DH + c);
#pragma unroll
        for (int q = 0; q < 8; ++q) r[q] += bf2f((u16)rv[q]);
    }
    s16x8 ov;
#pragma unroll
    for (int q = 0; q < 8; ++q) ov[q] = (short)f2bf(r[q]);
    *(s16x8*)(out + i * DH + c) = ov;
}

// ---------------- per-graph boundaries ----------------
__global__ __launch_bounds__(256) void graph_bounds_kernel(const int* __restrict__ batch,
                                                           int* __restrict__ gp) {
    int g = blockIdx.x * blockDim.x + threadIdx.x;
    if (g > NG) return;
    int lo = 0, hi = N_NODES;
    while (lo < hi) {
        int mid = (lo + hi) >> 1;
        if (batch[mid] < g) lo = mid + 1; else hi = mid;
    }
    gp[g] = lo;
}

// ---------------- segmented mean pool (bf16 in, fp32 out) ----------------
__global__ __launch_bounds__(128) void pool_kernel(const u16* __restrict__ h,
                                                   const int* __restrict__ gp,
                                                   float* __restrict__ pooled) {
    const int g = blockIdx.x;
    const int j = threadIdx.x;
    const int beg = gp[g];
    const int end = gp[g + 1];
    float s = 0.0f;
    for (int i = beg; i < end; ++i) s += bf2f(h[(long)i * DH + j]);
    pooled[(long)g * DH + j] = s / fmaxf((float)(end - beg), 1.0f);
}

// ---------------- MLP head ----------------
__global__ __launch_bounds__(64) void head_kernel(const float* __restrict__ pooled,
                                                  const float* __restrict__ fc1w,
                                                  const float* __restrict__ fc1b,
                                                  const float* __restrict__ fc2w,
                                                  const float* __restrict__ fc2b,
                                                  float* __restrict__ out) {
    const int g = blockIdx.x;
    const int j = threadIdx.x;
    __shared__ float p[DH];
    p[j]      = pooled[(long)g * DH + j];
    p[j + 64] = pooled[(long)g * DH + 64 + j];
    __syncthreads();

    float acc = 0.0f;
#pragma unroll 4
    for (int k = 0; k < DH; ++k) acc = fmaf(p[k], fc1w[(long)k * 64 + j], acc);
    const float h1 = fmaxf(acc + fc1b[j], 0.0f);
    float v = h1 * fc2w[j];
#pragma unroll
    for (int off = 32; off > 0; off >>= 1) v += __shfl_down(v, off);
    if (j == 0) out[g] = 1.0f / (1.0f + expf(-(v + fc2b[0])));
}

// ---------------- launch ----------------
extern "C" void kernel_launch(void* const* d_in, const int* in_sizes, int n_in,
                              void* d_out, int out_size, void* d_ws, size_t ws_size,
                              hipStream_t stream) {
    const float* x     = (const float*)d_in[0];
    const int*   ei    = (const int*)d_in[1];
    const int*   batch = (const int*)d_in[2];
    const float* W1 = (const float*)d_in[3];
    const float* b1 = (const float*)d_in[4];
    const float* g1 = (const float*)d_in[5];
    const float* t1 = (const float*)d_in[6];
    const float* m1 = (const float*)d_in[7];
    const float* v1 = (const float*)d_in[8];
    const float* W2 = (const float*)d_in[9];
    const float* b2 = (const float*)d_in[10];
    const float* g2 = (const float*)d_in[11];
    const float* t2 = (const float*)d_in[12];
    const float* m2 = (const float*)d_in[13];
    const float* v2 = (const float*)d_in[14];
    const float* W3 = (const float*)d_in[15];
    const float* b3 = (const float*)d_in[16];
    const float* g3 = (const float*)d_in[17];
    const float* t3 = (const float*)d_in[18];
    const float* m3 = (const float*)d_in[19];
    const float* v3 = (const float*)d_in[20];
    const float* fc1w = (const float*)d_in[21];
    const float* fc1b = (const float*)d_in[22];
    const float* fc2w = (const float*)d_in[23];
    const float* fc2b = (const float*)d_in[24];

    const int* src = ei;
    const int* dst = ei + N_EDGES;

    // ---- workspace ----
    char* ws = (char*)d_ws;
    size_t off = 0;
    auto alloc = [&](size_t bytes) -> char* {
        char* p = ws + off;
        off = (off + bytes + 511) & ~(size_t)511;
        return p;
    };
    float* deg     = (float*)alloc((size_t)N_NODES * 4);
    float* dis     = (float*)alloc((size_t)N_NODES * 4);
    int*   deg_i   = (int*)  alloc((size_t)N_NODES * 4);
    int*   row_ptr = (int*)  alloc(((size_t)N_NODES + 1) * 4);
    int*   cursor  = (int*)  alloc((size_t)N_NODES * 4);
    int*   blk     = (int*)  alloc((size_t)N_SCAN_BLK * 4);
    int*   col     = (int*)  alloc((size_t)N_EDGES * 4);
    float* val     = (float*)alloc((size_t)N_EDGES * 4);
    int*   gp      = (int*)  alloc((size_t)(NG + 1) * 4);
    float* pooled  = (float*)alloc((size_t)NG * DH * 4);
    float* bnsc    = (float*)alloc((size_t)3 * DH * 4);
    float* bnsh    = (float*)alloc((size_t)3 * DH * 4);
    u16*   xb      = (u16*)  alloc((size_t)N_NODES * DIN * 2);
    u16*   Wt1     = (u16*)  alloc((size_t)DH * DIN * 2);
    u16*   Wt2     = (u16*)  alloc((size_t)DH * DH * 2);
    u16*   Wt3     = (u16*)  alloc((size_t)DH * DH * 2);
    u16*   bufB    = (u16*)  alloc((size_t)N_NODES * DH * 2);
    u16*   bufA    = (u16*)  alloc((size_t)N_NODES * DH * 2);

    const int TPB = 256;
    const int gEdge  = (N_EDGES + TPB - 1) / TPB;
    const int gNode  = (N_NODES + TPB - 1) / TPB;
    const int gGemm  = (N_NODES + 63) / 64;                              // 1563
    const int gAgg   = (int)(((long)N_NODES * 16 + TPB - 1) / TPB);      // 6250

    // ---- prep ----
    hipMemsetAsync(deg, 0, (size_t)N_NODES * 4, stream);
    hipMemsetAsync(cursor, 0, (size_t)N_NODES * 4, stream);
    deg_kernel<<<gEdge, TPB, 0, stream>>>(dst, deg, N_EDGES);
    dis_kernel<<<gNode, TPB, 0, stream>>>(deg, dis, deg_i, N_NODES);
    scan1_kernel<<<N_SCAN_BLK, SCAN_TPB, 0, stream>>>(deg_i, row_ptr, blk, N_NODES);
    scan2_kernel<<<1, 512, 0, stream>>>(blk, row_ptr, N_SCAN_BLK, N_NODES);
    scan3_kernel<<<N_SCAN_BLK, SCAN_TPB, 0, stream>>>(row_ptr, blk, N_NODES);
    build_csr_kernel<<<gEdge, TPB, 0, stream>>>(src, dst, dis, row_ptr, cursor, col, val,
                                                N_EDGES);
    graph_bounds_kernel<<<3, 256, 0, stream>>>(batch, gp);

    xcvt_kernel<<<(int)(((long)N_NODES * DIN / 8 + TPB - 1) / TPB), TPB, 0, stream>>>(
        x, xb, (long)N_NODES * DIN);
    wt_kernel<<<(DIN * DH + TPB - 1) / TPB, TPB, 0, stream>>>(W1, Wt1, DIN, DH);
    wt_kernel<<<(DH * DH + TPB - 1) / TPB, TPB, 0, stream>>>(W2, Wt2, DH, DH);
    wt_kernel<<<(DH * DH + TPB - 1) / TPB, TPB, 0, stream>>>(W3, Wt3, DH, DH);
    bn_prep_kernel<<<2, TPB, 0, stream>>>(b1, g1, t1, m1, v1, b2, g2, t2, m2, v2,
                                          b3, g3, t3, m3, v3, bnsc, bnsh);

    // ---- layer 1 ----
    gemm_mfma<DIN><<<gGemm, TPB, 0, stream>>>(xb, Wt1, bufB, N_NODES);
    agg_epi_kernel<false><<<gAgg, TPB, 0, stream>>>(bufB, row_ptr, col, val, dis,
                                                    bnsc, bnsh, bufA, N_NODES);
    // ---- layer 2 (residual, in-place) ----
    gemm_mfma<DH><<<gGemm, TPB, 0, stream>>>(bufA, Wt2, bufB, N_NODES);
    agg_epi_kernel<true><<<gAgg, TPB, 0, stream>>>(bufB, row_ptr, col, val, dis,
                                                   bnsc + DH, bnsh + DH, bufA, N_NODES);
    // ---- layer 3 ----
    gemm_mfma<DH><<<gGemm, TPB, 0, stream>>>(bufA, Wt3, bufB, N_NODES);
    agg_epi_kernel<false><<<gAgg, TPB, 0, stream>>>(bufB, row_ptr, col, val, dis,
                                                    bnsc + 2 * DH, bnsh + 2 * DH, bufA,
                                                    N_NODES);

    // ---- pool + head ----
    pool_kernel<<<NG, 128, 0, stream>>>(bufA, gp, pooled);
    head_kernel<<<NG, 64, 0, stream>>>(pooled, fc1w, fc1b, fc2w, fc2b, (float*)d_out);
}

// Round 5
// 319.616 us; speedup vs baseline: 11.7490x; 1.1822x over previous
//
#include <hip/hip_runtime.h>
#include <math.h>

#define N_NODES 100000
#define N_EDGES 600000
#define DIN     64
#define DH      128
#define NG      512
#define EPS_BN  1e-5f
#define SCAN_TPB 256
#define N_SCAN_BLK ((N_NODES + SCAN_TPB - 1) / SCAN_TPB)   // 391

typedef unsigned short u16;
typedef short s16x8 __attribute__((ext_vector_type(8)));
typedef float f32x4 __attribute__((ext_vector_type(4)));

__device__ __forceinline__ u16 f2bf(float x) {
    unsigned u = __builtin_bit_cast(unsigned, x);
    u += 0x7fffu + ((u >> 16) & 1u);   // round-to-nearest-even
    return (u16)(u >> 16);
}
__device__ __forceinline__ float bf2f(u16 h) {
    unsigned u = ((unsigned)h) << 16;
    return __builtin_bit_cast(float, u);
}

// ---------------- degree histogram ----------------
__global__ __launch_bounds__(256) void deg_kernel(const int* __restrict__ dst,
                                                  float* __restrict__ deg, int E) {
    int e = blockIdx.x * blockDim.x + threadIdx.x;
    if (e < E) atomicAdd(&deg[dst[e]], 1.0f);
}

__global__ __launch_bounds__(256) void dis_kernel(const float* __restrict__ deg,
                                                  float* __restrict__ dis,
                                                  int* __restrict__ deg_i, int n) {
    int i = blockIdx.x * blockDim.x + threadIdx.x;
    if (i < n) {
        float d = deg[i];
        dis[i] = rsqrtf(d + 1.0f);   // +1 self loop
        deg_i[i] = (int)d;
    }
}

// ---------------- multi-block scan ----------------
__global__ __launch_bounds__(SCAN_TPB) void scan1_kernel(const int* __restrict__ deg_i,
                                                         int* __restrict__ row_ptr,
                                                         int* __restrict__ blk, int n) {
    __shared__ int sm[SCAN_TPB];
    const int t = threadIdx.x;
    const int i = blockIdx.x * SCAN_TPB + t;
    const int v = (i < n) ? deg_i[i] : 0;
    sm[t] = v;
    __syncthreads();
#pragma unroll
    for (int off = 1; off < SCAN_TPB; off <<= 1) {
        int u = (t >= off) ? sm[t - off] : 0;
        __syncthreads();
        sm[t] += u;
        __syncthreads();
    }
    if (i < n) row_ptr[i] = sm[t] - v;
    if (t == SCAN_TPB - 1) blk[blockIdx.x] = sm[t];
}

__global__ __launch_bounds__(512) void scan2_kernel(int* __restrict__ blk,
                                                    int* __restrict__ row_ptr,
                                                    int nblk, int n) {
    __shared__ int sm[512];
    const int t = threadIdx.x;
    const int v = (t < nblk) ? blk[t] : 0;
    sm[t] = v;
    __syncthreads();
#pragma unroll
    for (int off = 1; off < 512; off <<= 1) {
        int u = (t >= off) ? sm[t - off] : 0;
        __syncthreads();
        sm[t] += u;
        __syncthreads();
    }
    if (t < nblk) blk[t] = sm[t] - v;
    if (t == nblk - 1) row_ptr[n] = sm[t];
}

__global__ __launch_bounds__(SCAN_TPB) void scan3_kernel(int* __restrict__ row_ptr,
                                                         const int* __restrict__ blk, int n) {
    const int i = blockIdx.x * SCAN_TPB + threadIdx.x;
    if (i < n) row_ptr[i] += blk[blockIdx.x];
}

// ---------------- scatter edges into CSR ----------------
__global__ __launch_bounds__(256) void build_csr_kernel(const int* __restrict__ src,
                                                        const int* __restrict__ dst,
                                                        const float* __restrict__ dis,
                                                        const int* __restrict__ row_ptr,
                                                        int* __restrict__ cursor,
                                                        int* __restrict__ col,
                                                        float* __restrict__ val, int E) {
    int e = blockIdx.x * blockDim.x + threadIdx.x;
    if (e >= E) return;
    const int s = src[e];
    const int d = dst[e];
    const int p = atomicAdd(&cursor[d], 1);
    const int idx = row_ptr[d] + p;
    col[idx] = s;
    val[idx] = dis[s] * dis[d];
}

// ---------------- fp32 -> bf16 convert (x) ----------------
__global__ __launch_bounds__(256) void xcvt_kernel(const float* __restrict__ x,
                                                   u16* __restrict__ xb, long n) {
    long i = ((long)blockIdx.x * blockDim.x + threadIdx.x) * 8;
    if (i >= n) return;
    const float4 a = *(const float4*)(x + i);
    const float4 b = *(const float4*)(x + i + 4);
    s16x8 o;
    o[0] = (short)f2bf(a.x); o[1] = (short)f2bf(a.y);
    o[2] = (short)f2bf(a.z); o[3] = (short)f2bf(a.w);
    o[4] = (short)f2bf(b.x); o[5] = (short)f2bf(b.y);
    o[6] = (short)f2bf(b.z); o[7] = (short)f2bf(b.w);
    *(s16x8*)(xb + i) = o;
}

// ---------------- W[K][N] fp32 -> Wt[N][K] bf16 ----------------
__global__ __launch_bounds__(256) void wt_kernel(const float* __restrict__ W,
                                                 u16* __restrict__ Wt, int K, int N) {
    int idx = blockIdx.x * blockDim.x + threadIdx.x;
    if (idx >= K * N) return;
    int k = idx / N, n = idx % N;
    Wt[(long)n * K + k] = f2bf(W[idx]);
}

// ---------------- fold BN into scale/shift (3 layers) ----------------
__global__ __launch_bounds__(256) void bn_prep_kernel(
    const float* b1, const float* g1, const float* bb1, const float* m1, const float* v1,
    const float* b2, const float* g2, const float* bb2, const float* m2, const float* v2,
    const float* b3, const float* g3, const float* bb3, const float* m3, const float* v3,
    float* __restrict__ sc, float* __restrict__ sh) {
    int i = blockIdx.x * blockDim.x + threadIdx.x;
    if (i >= 3 * DH) return;
    int l = i >> 7, c = i & (DH - 1);
    const float* bc = l == 0 ? b1 : (l == 1 ? b2 : b3);
    const float* g  = l == 0 ? g1 : (l == 1 ? g2 : g3);
    const float* bb = l == 0 ? bb1 : (l == 1 ? bb2 : bb3);
    const float* m  = l == 0 ? m1 : (l == 1 ? m2 : m3);
    const float* v  = l == 0 ? v1 : (l == 1 ? v2 : v3);
    float s = g[c] * rsqrtf(v[c] + EPS_BN);
    sc[i] = s;
    sh[i] = (bc[c] - m[c]) * s + bb[c];
}

// ---------------- MFMA GEMM: C[M,128] = A[M,K] @ Wt^T, bf16 in/out, fp32 acc ----------------
template <int K>
__global__ __launch_bounds__(256) void gemm_mfma(const u16* __restrict__ A,   // [M][K] bf16
                                                 const u16* __restrict__ Wt,  // [128][K] bf16
                                                 u16* __restrict__ C,         // [M][128] bf16
                                                 int M) {
    const int wave = threadIdx.x >> 6;
    const int lane = threadIdx.x & 63;
    const int r16 = lane & 15;   // A row-in-tile / B col-in-tile
    const int kc  = lane >> 4;   // k-chunk 0..3 (8 bf16 each)
    const long row0 = (long)blockIdx.x * 64 + wave * 16;

    f32x4 acc[8];
#pragma unroll
    for (int t = 0; t < 8; ++t)
#pragma unroll
        for (int q = 0; q < 4; ++q) acc[t][q] = 0.0f;

    long arow = row0 + r16;
    if (arow >= M) arow = M - 1;
    const u16* ap = A + arow * K + kc * 8;

#pragma unroll
    for (int ks = 0; ks < K; ks += 32) {
        const s16x8 a = *(const s16x8*)(ap + ks);
#pragma unroll
        for (int t = 0; t < 8; ++t) {
            const s16x8 b = *(const s16x8*)(Wt + (long)(t * 16 + r16) * K + ks + kc * 8);
            acc[t] = __builtin_amdgcn_mfma_f32_16x16x32_bf16(a, b, acc[t], 0, 0, 0);
        }
    }

    // D: col = t*16 + (lane&15), row = row0 + (lane>>4)*4 + r
#pragma unroll
    for (int r = 0; r < 4; ++r) {
        const long row = row0 + kc * 4 + r;
        if (row < M) {
            u16* cp = C + row * DH + r16;
#pragma unroll
            for (int t = 0; t < 8; ++t) cp[t * 16] = f2bf(acc[t][r]);
        }
    }
}

// ---------- fused: CSR gather-sum + selfloop + BN(scale/shift) + ReLU [+res], bf16 ----------
template <bool RES>
__global__ __launch_bounds__(256) void agg_epi_kernel(const u16* __restrict__ H,
                                                      const int* __restrict__ row_ptr,
                                                      const int* __restrict__ col,
                                                      const float* __restrict__ val,
                                                      const float* __restrict__ dis,
                                                      const float* __restrict__ scl,
                                                      const float* __restrict__ shf,
                                                      u16* __restrict__ out, int n) {
    const long t = (long)blockIdx.x * blockDim.x + threadIdx.x;
    const int lane = (int)(t & 15);
    const long i = t >> 4;
    if (i >= n) return;
    const int c = lane * 8;

    float d2 = dis[i];
    d2 *= d2;
    float acc[8];
    const s16x8 hv = *(const s16x8*)(H + i * DH + c);
#pragma unroll
    for (int q = 0; q < 8; ++q) acc[q] = bf2f((u16)hv[q]) * d2;   // self-loop

    const int beg = row_ptr[i];
    const int end = row_ptr[i + 1];
    for (int e = beg; e < end; ++e) {
        const int s = col[e];
        const float nm = val[e];
        const s16x8 v = *(const s16x8*)(H + (long)s * DH + c);
#pragma unroll
        for (int q = 0; q < 8; ++q) acc[q] = fmaf(bf2f((u16)v[q]), nm, acc[q]);
    }

    const float4 s0 = *(const float4*)(scl + c);
    const float4 s1 = *(const float4*)(scl + c + 4);
    const float4 f0 = *(const float4*)(shf + c);
    const float4 f1 = *(const float4*)(shf + c + 4);
    const float sv[8] = {s0.x, s0.y, s0.z, s0.w, s1.x, s1.y, s1.z, s1.w};
    const float fv[8] = {f0.x, f0.y, f0.z, f0.w, f1.x, f1.y, f1.z, f1.w};

    float r[8];
#pragma unroll
    for (int q = 0; q < 8; ++q) r[q] = fmaxf(fmaf(acc[q], sv[q], fv[q]), 0.0f);
    if (RES) {
        const s16x8 rv = *(const s16x8*)(out + i * DH + c);
#pragma unroll
        for (int q = 0; q < 8; ++q) r[q] += bf2f((u16)rv[q]);
    }
    s16x8 ov;
#pragma unroll
    for (int q = 0; q < 8; ++q) ov[q] = (short)f2bf(r[q]);
    *(s16x8*)(out + i * DH + c) = ov;
}

// ---------------- per-graph boundaries ----------------
__global__ __launch_bounds__(256) void graph_bounds_kernel(const int* __restrict__ batch,
                                                           int* __restrict__ gp) {
    int g = blockIdx.x * blockDim.x + threadIdx.x;
    if (g > NG) return;
    int lo = 0, hi = N_NODES;
    while (lo < hi) {
        int mid = (lo + hi) >> 1;
        if (batch[mid] < g) lo = mid + 1; else hi = mid;
    }
    gp[g] = lo;
}

// ------- segmented mean pool: 1 block/graph, 16 node-subgroups x 16 lanes, LDS reduce -------
__global__ __launch_bounds__(256) void pool_kernel(const u16* __restrict__ h,
                                                   const int* __restrict__ gp,
                                                   float* __restrict__ pooled) {
    const int g = blockIdx.x;
    const int t = threadIdx.x;
    const int grp = t >> 4;        // node subgroup 0..15
    const int cl = t & 15;         // channel chunk
    const int c = cl * 8;
    const int beg = gp[g];
    const int end = gp[g + 1];

    float acc[8] = {0, 0, 0, 0, 0, 0, 0, 0};
    for (int i = beg + grp; i < end; i += 16) {
        const s16x8 v = *(const s16x8*)(h + (long)i * DH + c);
#pragma unroll
        for (int q = 0; q < 8; ++q) acc[q] += bf2f((u16)v[q]);
    }

    __shared__ float sm[16][DH];
#pragma unroll
    for (int q = 0; q < 8; ++q) sm[grp][c + q] = acc[q];
    __syncthreads();

    if (t < DH) {
        float s = 0.0f;
#pragma unroll
        for (int r = 0; r < 16; ++r) s += sm[r][t];
        pooled[(long)g * DH + t] = s / fmaxf((float)(end - beg), 1.0f);
    }
}

// ---------------- MLP head ----------------
__global__ __launch_bounds__(64) void head_kernel(const float* __restrict__ pooled,
                                                  const float* __restrict__ fc1w,
                                                  const float* __restrict__ fc1b,
                                                  const float* __restrict__ fc2w,
                                                  const float* __restrict__ fc2b,
                                                  float* __restrict__ out) {
    const int g = blockIdx.x;
    const int j = threadIdx.x;
    __shared__ float p[DH];
    p[j]      = pooled[(long)g * DH + j];
    p[j + 64] = pooled[(long)g * DH + 64 + j];
    __syncthreads();

    float acc = 0.0f;
#pragma unroll 4
    for (int k = 0; k < DH; ++k) acc = fmaf(p[k], fc1w[(long)k * 64 + j], acc);
    const float h1 = fmaxf(acc + fc1b[j], 0.0f);
    float v = h1 * fc2w[j];
#pragma unroll
    for (int off = 32; off > 0; off >>= 1) v += __shfl_down(v, off);
    if (j == 0) out[g] = 1.0f / (1.0f + expf(-(v + fc2b[0])));
}

// ---------------- launch ----------------
extern "C" void kernel_launch(void* const* d_in, const int* in_sizes, int n_in,
                              void* d_out, int out_size, void* d_ws, size_t ws_size,
                              hipStream_t stream) {
    const float* x     = (const float*)d_in[0];
    const int*   ei    = (const int*)d_in[1];
    const int*   batch = (const int*)d_in[2];
    const float* W1 = (const float*)d_in[3];
    const float* b1 = (const float*)d_in[4];
    const float* g1 = (const float*)d_in[5];
    const float* t1 = (const float*)d_in[6];
    const float* m1 = (const float*)d_in[7];
    const float* v1 = (const float*)d_in[8];
    const float* W2 = (const float*)d_in[9];
    const float* b2 = (const float*)d_in[10];
    const float* g2 = (const float*)d_in[11];
    const float* t2 = (const float*)d_in[12];
    const float* m2 = (const float*)d_in[13];
    const float* v2 = (const float*)d_in[14];
    const float* W3 = (const float*)d_in[15];
    const float* b3 = (const float*)d_in[16];
    const float* g3 = (const float*)d_in[17];
    const float* t3 = (const float*)d_in[18];
    const float* m3 = (const float*)d_in[19];
    const float* v3 = (const float*)d_in[20];
    const float* fc1w = (const float*)d_in[21];
    const float* fc1b = (const float*)d_in[22];
    const float* fc2w = (const float*)d_in[23];
    const float* fc2b = (const float*)d_in[24];

    const int* src = ei;
    const int* dst = ei + N_EDGES;

    // ---- workspace ----
    char* ws = (char*)d_ws;
    size_t off = 0;
    auto alloc = [&](size_t bytes) -> char* {
        char* p = ws + off;
        off = (off + bytes + 511) & ~(size_t)511;
        return p;
    };
    float* deg     = (float*)alloc((size_t)N_NODES * 4);
    float* dis     = (float*)alloc((size_t)N_NODES * 4);
    int*   deg_i   = (int*)  alloc((size_t)N_NODES * 4);
    int*   row_ptr = (int*)  alloc(((size_t)N_NODES + 1) * 4);
    int*   cursor  = (int*)  alloc((size_t)N_NODES * 4);
    int*   blk     = (int*)  alloc((size_t)N_SCAN_BLK * 4);
    int*   col     = (int*)  alloc((size_t)N_EDGES * 4);
    float* val     = (float*)alloc((size_t)N_EDGES * 4);
    int*   gp      = (int*)  alloc((size_t)(NG + 1) * 4);
    float* pooled  = (float*)alloc((size_t)NG * DH * 4);
    float* bnsc    = (float*)alloc((size_t)3 * DH * 4);
    float* bnsh    = (float*)alloc((size_t)3 * DH * 4);
    u16*   xb      = (u16*)  alloc((size_t)N_NODES * DIN * 2);
    u16*   Wt1     = (u16*)  alloc((size_t)DH * DIN * 2);
    u16*   Wt2     = (u16*)  alloc((size_t)DH * DH * 2);
    u16*   Wt3     = (u16*)  alloc((size_t)DH * DH * 2);
    u16*   bufB    = (u16*)  alloc((size_t)N_NODES * DH * 2);
    u16*   bufA    = (u16*)  alloc((size_t)N_NODES * DH * 2);

    const int TPB = 256;
    const int gEdge  = (N_EDGES + TPB - 1) / TPB;
    const int gNode  = (N_NODES + TPB - 1) / TPB;
    const int gGemm  = (N_NODES + 63) / 64;                              // 1563
    const int gAgg   = (int)(((long)N_NODES * 16 + TPB - 1) / TPB);      // 6250

    // ---- prep ----
    hipMemsetAsync(deg, 0, (size_t)N_NODES * 4, stream);
    hipMemsetAsync(cursor, 0, (size_t)N_NODES * 4, stream);
    deg_kernel<<<gEdge, TPB, 0, stream>>>(dst, deg, N_EDGES);
    dis_kernel<<<gNode, TPB, 0, stream>>>(deg, dis, deg_i, N_NODES);
    scan1_kernel<<<N_SCAN_BLK, SCAN_TPB, 0, stream>>>(deg_i, row_ptr, blk, N_NODES);
    scan2_kernel<<<1, 512, 0, stream>>>(blk, row_ptr, N_SCAN_BLK, N_NODES);
    scan3_kernel<<<N_SCAN_BLK, SCAN_TPB, 0, stream>>>(row_ptr, blk, N_NODES);
    build_csr_kernel<<<gEdge, TPB, 0, stream>>>(src, dst, dis, row_ptr, cursor, col, val,
                                                N_EDGES);
    graph_bounds_kernel<<<3, 256, 0, stream>>>(batch, gp);

    xcvt_kernel<<<(int)(((long)N_NODES * DIN / 8 + TPB - 1) / TPB), TPB, 0, stream>>>(
        x, xb, (long)N_NODES * DIN);
    wt_kernel<<<(DIN * DH + TPB - 1) / TPB, TPB, 0, stream>>>(W1, Wt1, DIN, DH);
    wt_kernel<<<(DH * DH + TPB - 1) / TPB, TPB, 0, stream>>>(W2, Wt2, DH, DH);
    wt_kernel<<<(DH * DH + TPB - 1) / TPB, TPB, 0, stream>>>(W3, Wt3, DH, DH);
    bn_prep_kernel<<<2, TPB, 0, stream>>>(b1, g1, t1, m1, v1, b2, g2, t2, m2, v2,
                                          b3, g3, t3, m3, v3, bnsc, bnsh);

    // ---- layer 1 ----
    gemm_mfma<DIN><<<gGemm, TPB, 0, stream>>>(xb, Wt1, bufB, N_NODES);
    agg_epi_kernel<false><<<gAgg, TPB, 0, stream>>>(bufB, row_ptr, col, val, dis,
                                                    bnsc, bnsh, bufA, N_NODES);
    // ---- layer 2 (residual, in-place) ----
    gemm_mfma<DH><<<gGemm, TPB, 0, stream>>>(bufA, Wt2, bufB, N_NODES);
    agg_epi_kernel<true><<<gAgg, TPB, 0, stream>>>(bufB, row_ptr, col, val, dis,
                                                   bnsc + DH, bnsh + DH, bufA, N_NODES);
    // ---- layer 3 ----
    gemm_mfma<DH><<<gGemm, TPB, 0, stream>>>(bufA, Wt3, bufB, N_NODES);
    agg_epi_kernel<false><<<gAgg, TPB, 0, stream>>>(bufB, row_ptr, col, val, dis,
                                                    bnsc + 2 * DH, bnsh + 2 * DH, bufA,
                                                    N_NODES);

    // ---- pool + head ----
    pool_kernel<<<NG, TPB, 0, stream>>>(bufA, gp, pooled);
    head_kernel<<<NG, 64, 0, stream>>>(pooled, fc1w, fc1b, fc2w, fc2b, (float*)d_out);
}